// Round 1
// baseline (640.207 us; speedup 1.0000x reference)
//
#include <hip/hip_runtime.h>
#include <stdint.h>

#define IN_F   4096
#define OUT_F  4096
#define TOKENS 8192
#define RANK   16
#define WORDS  256

#define BM 128
#define BN 128
#define BK 32

typedef unsigned short u16;
typedef __attribute__((ext_vector_type(8))) short bf16x8;
typedef __attribute__((ext_vector_type(4))) float f32x4;

// async global->LDS, 16B per lane. LDS dest must be wave-uniform base; HW adds lane*16.
#define GLDS16(g, l) __builtin_amdgcn_global_load_lds( \
    (__attribute__((address_space(1))) void*)(g),      \
    (__attribute__((address_space(3))) void*)(l), 16, 0, 0)

__device__ __forceinline__ u16 bf16bits(float f) {
    unsigned int u = __builtin_bit_cast(unsigned int, f);
    unsigned int lsb = (u >> 16) & 1u;
    u += 0x7fffu + lsb;              // round-to-nearest-even
    return (u16)(u >> 16);
}

// ---------------- prep: x fp32 -> bf16 ----------------
__global__ __launch_bounds__(256) void k_cvt_x(const float4* __restrict__ x,
                                               ushort4* __restrict__ xb) {
    int i = blockIdx.x * 256 + threadIdx.x;
    float4 v = x[i];
    ushort4 o;
    o.x = bf16bits(v.x); o.y = bf16bits(v.y);
    o.z = bf16bits(v.z); o.w = bf16bits(v.w);
    xb[i] = o;
}

// ---------------- prep: W[o,i] = alpha*T + mu + lora  (bf16) ----------------
__global__ __launch_bounds__(256) void k_build_w(const int* __restrict__ packed,
                                                 const float* __restrict__ alpha,
                                                 const float* __restrict__ mu,
                                                 const float* __restrict__ lA,
                                                 const float* __restrict__ lB,
                                                 u16* __restrict__ W) {
    int idx = blockIdx.x * 256 + threadIdx.x;   // [0, OUT_F*WORDS)
    int o = idx >> 8;
    int w = idx & 255;

    float lacc[16];
#pragma unroll
    for (int k = 0; k < 16; k++) lacc[k] = 0.f;

#pragma unroll
    for (int r = 0; r < RANK; r++) {
        float br = lB[o * RANK + r];
        const float4* ap = (const float4*)(lA + (size_t)r * IN_F + (w << 4));
        float4 a0 = ap[0], a1 = ap[1], a2 = ap[2], a3 = ap[3];
        lacc[0]  += br * a0.x; lacc[1]  += br * a0.y; lacc[2]  += br * a0.z; lacc[3]  += br * a0.w;
        lacc[4]  += br * a1.x; lacc[5]  += br * a1.y; lacc[6]  += br * a1.z; lacc[7]  += br * a1.w;
        lacc[8]  += br * a2.x; lacc[9]  += br * a2.y; lacc[10] += br * a2.z; lacc[11] += br * a2.w;
        lacc[12] += br * a3.x; lacc[13] += br * a3.y; lacc[14] += br * a3.z; lacc[15] += br * a3.w;
    }

    int p = packed[idx];
    float a = alpha[o], m = mu[o];
    union { u16 u[16]; uint4 q[2]; } ob;
#pragma unroll
    for (int k = 0; k < 16; k++) {
        float t = (float)(((p >> (2 * k)) & 3) - 1);
        ob.u[k] = bf16bits(fmaf(a, t, m + lacc[k]));
    }
    uint4* dst = (uint4*)(W + (size_t)idx * 16);
    dst[0] = ob.q[0];
    dst[1] = ob.q[1];
}

// ---------------- main GEMM: out = A * W^T + bias ----------------
// ABF=1: A is bf16 [TOKENS,IN_F]; ABF=0: A is fp32, converted in the K-loop.
template <int ABF>
__global__ __launch_bounds__(256, 2) void k_gemm(const void* __restrict__ Ap,
                                                 const u16* __restrict__ W,
                                                 const float* __restrict__ bias,
                                                 float* __restrict__ out) {
    constexpr int A_TILE_BYTES = BM * BK * (ABF ? 2 : 4);     // 8 or 16 KiB
    __shared__ unsigned char smem[A_TILE_BYTES + BN * BK * 2];
    unsigned char* smA = smem;
    unsigned char* smB = smem + A_TILE_BYTES;

    const int tid  = threadIdx.x;
    const int lane = tid & 63;
    const int wv   = tid >> 6;
    const int wm   = (wv >> 1) * 64;
    const int wn   = (wv & 1) * 64;
    const int fr   = lane & 15;          // row within 16x16 frag
    const int fk   = (lane >> 4) * 8;    // k offset within BK

    const int m0 = blockIdx.y * BM;
    const int n0 = blockIdx.x * BN;

    const int wbase = (tid >> 6) * 64 * 16;  // wave-uniform LDS chunk base (bytes)

    f32x4 acc[4][4] = {};

    for (int k0 = 0; k0 < IN_F; k0 += BK) {
        __syncthreads();
        // stage B tile (bf16 W): 512 x 16B chunks, 2 per thread
#pragma unroll
        for (int i = 0; i < 2; i++) {
            int c = i * 256 + tid;
            int row = c >> 2, cc = c & 3;
            const u16* g = W + (size_t)(n0 + row) * IN_F + k0 + cc * 8;
            GLDS16(g, smB + i * 256 * 16 + wbase);
        }
        // stage A tile
        if (ABF) {
            const u16* xb = (const u16*)Ap;
#pragma unroll
            for (int i = 0; i < 2; i++) {
                int c = i * 256 + tid;
                int row = c >> 2, cc = c & 3;
                const u16* g = xb + (size_t)(m0 + row) * IN_F + k0 + cc * 8;
                GLDS16(g, smA + i * 256 * 16 + wbase);
            }
        } else {
            const float* xf = (const float*)Ap;
#pragma unroll
            for (int i = 0; i < 4; i++) {
                int c = i * 256 + tid;
                int row = c >> 3, cc = c & 7;
                const float* g = xf + (size_t)(m0 + row) * IN_F + k0 + cc * 4;
                GLDS16(g, smA + i * 256 * 16 + wbase);
            }
        }
        __syncthreads();

        bf16x8 afr[4], bfr[4];
#pragma unroll
        for (int mt = 0; mt < 4; mt++) {
            int row = wm + mt * 16 + fr;
            if (ABF) {
                afr[mt] = *(const bf16x8*)(smA + ((size_t)row * BK + fk) * 2);
            } else {
                const float* ap = (const float*)smA + row * BK + fk;
                float4 v0 = *(const float4*)ap;
                float4 v1 = *(const float4*)(ap + 4);
                union { bf16x8 v; u16 u[8]; } pk;
                pk.u[0] = bf16bits(v0.x); pk.u[1] = bf16bits(v0.y);
                pk.u[2] = bf16bits(v0.z); pk.u[3] = bf16bits(v0.w);
                pk.u[4] = bf16bits(v1.x); pk.u[5] = bf16bits(v1.y);
                pk.u[6] = bf16bits(v1.z); pk.u[7] = bf16bits(v1.w);
                afr[mt] = pk.v;
            }
        }
#pragma unroll
        for (int nt = 0; nt < 4; nt++) {
            int row = wn + nt * 16 + fr;
            bfr[nt] = *(const bf16x8*)(smB + ((size_t)row * BK + fk) * 2);
        }
#pragma unroll
        for (int mt = 0; mt < 4; mt++)
#pragma unroll
            for (int nt = 0; nt < 4; nt++)
                acc[mt][nt] = __builtin_amdgcn_mfma_f32_16x16x32_bf16(
                    afr[mt], bfr[nt], acc[mt][nt], 0, 0, 0);
    }

    // epilogue: C[row][col] = acc + bias[col]
    const int r0 = (lane >> 4) * 4;
    const int c0 = lane & 15;
#pragma unroll
    for (int nt = 0; nt < 4; nt++) {
        int col = n0 + wn + nt * 16 + c0;
        float bv = bias[col];
#pragma unroll
        for (int mt = 0; mt < 4; mt++) {
            int row = m0 + wm + mt * 16 + r0;
            float* op = out + (size_t)row * OUT_F + col;
#pragma unroll
            for (int r = 0; r < 4; r++)
                op[(size_t)r * OUT_F] = acc[mt][nt][r] + bv;
        }
    }
}

extern "C" void kernel_launch(void* const* d_in, const int* in_sizes, int n_in,
                              void* d_out, int out_size, void* d_ws, size_t ws_size,
                              hipStream_t stream) {
    const float* x      = (const float*)d_in[0];
    const int*   packed = (const int*)d_in[1];
    const float* alpha  = (const float*)d_in[2];
    const float* mu     = (const float*)d_in[3];
    const float* bias   = (const float*)d_in[4];
    const float* lA     = (const float*)d_in[5];
    const float* lB     = (const float*)d_in[6];
    float* out = (float*)d_out;

    const size_t W_BYTES  = (size_t)OUT_F * IN_F * 2;   // 32 MiB
    const size_t XB_BYTES = (size_t)TOKENS * IN_F * 2;  // 64 MiB

    u16* W = (u16*)d_ws;
    k_build_w<<<dim3(OUT_F * WORDS / 256), dim3(256), 0, stream>>>(packed, alpha, mu, lA, lB, W);

    dim3 grid(OUT_F / BN, TOKENS / BM);  // (32, 64)
    if (ws_size >= W_BYTES + XB_BYTES) {
        u16* xb = (u16*)((char*)d_ws + W_BYTES);
        k_cvt_x<<<dim3(TOKENS * IN_F / 4 / 256), dim3(256), 0, stream>>>(
            (const float4*)x, (ushort4*)xb);
        k_gemm<1><<<grid, dim3(256), 0, stream>>>(xb, W, bias, out);
    } else {
        k_gemm<0><<<grid, dim3(256), 0, stream>>>(x, W, bias, out);
    }
}

// Round 2
// 497.278 us; speedup vs baseline: 1.2874x; 1.2874x over previous
//
#include <hip/hip_runtime.h>
#include <stdint.h>

#define IN_F   4096
#define OUT_F  4096
#define TOKENS 8192
#define RANK   16

#define BM 128
#define BN 128
#define BKI 64   // i8 K-tile (16x16x64 MFMA)

typedef unsigned short u16;
typedef __attribute__((ext_vector_type(8))) short bf16x8;
typedef __attribute__((ext_vector_type(4))) float f32x4;
typedef __attribute__((ext_vector_type(4))) int i32x4;

// async global->LDS, 16B/lane; LDS dest = wave-uniform base, HW adds lane*16
#define GLDS16(g, l) __builtin_amdgcn_global_load_lds( \
    (__attribute__((address_space(1))) void*)(g),      \
    (__attribute__((address_space(3))) void*)(l), 16, 0, 0)

__device__ __forceinline__ u16 bf16bits(float f) {
    unsigned int u = __builtin_bit_cast(unsigned int, f);
    unsigned int lsb = (u >> 16) & 1u;
    u += 0x7fffu + lsb;
    return (u16)(u >> 16);
}

__device__ __forceinline__ unsigned int quant4(float a, float b, float c, float d, float inv) {
    int qa = __float2int_rn(a * inv); qa = max(-127, min(127, qa));
    int qb = __float2int_rn(b * inv); qb = max(-127, min(127, qb));
    int qc = __float2int_rn(c * inv); qc = max(-127, min(127, qc));
    int qd = __float2int_rn(d * inv); qd = max(-127, min(127, qd));
    return (qa & 255) | ((qb & 255) << 8) | ((qc & 255) << 16) | ((qd & 255) << 24);
}

// ---- per-token stats + int8 quant + y = x*A^T (4 rows per block) ----
__global__ __launch_bounds__(256) void k_rowstat(const float* __restrict__ X,
                                                 const float* __restrict__ lA,
                                                 signed char* __restrict__ Xq,
                                                 float* __restrict__ sArr,
                                                 float* __restrict__ SArr,
                                                 u16* __restrict__ ypad) {
    const int tid = threadIdx.x;
    const int lane = tid & 63;
    const int wv = tid >> 6;
    const int t0 = blockIdx.x * 4;

    const float4* X4 = (const float4*)X;
    float4 xv[4][4];
#pragma unroll
    for (int t = 0; t < 4; t++)
#pragma unroll
        for (int j = 0; j < 4; j++)
            xv[t][j] = X4[(size_t)(t0 + t) * (IN_F / 4) + tid * 4 + j];

    __shared__ float redS[4][4], redM[4][4];  // [wave][row]
    __shared__ float bcInv[4];

    // per-row sum & absmax
#pragma unroll
    for (int t = 0; t < 4; t++) {
        float s = 0.f, m = 0.f;
#pragma unroll
        for (int j = 0; j < 4; j++) {
            float4 v = xv[t][j];
            s += v.x + v.y + v.z + v.w;
            m = fmaxf(m, fmaxf(fmaxf(fabsf(v.x), fabsf(v.y)), fmaxf(fabsf(v.z), fabsf(v.w))));
        }
#pragma unroll
        for (int off = 32; off > 0; off >>= 1) {
            s += __shfl_down(s, off);
            m = fmaxf(m, __shfl_down(m, off));
        }
        if (lane == 0) { redS[wv][t] = s; redM[wv][t] = m; }
    }
    __syncthreads();
    if (tid < 4) {
        float s = redS[0][tid] + redS[1][tid] + redS[2][tid] + redS[3][tid];
        float m = fmaxf(fmaxf(redM[0][tid], redM[1][tid]), fmaxf(redM[2][tid], redM[3][tid]));
        m = fmaxf(m, 1e-20f);
        SArr[t0 + tid] = s;
        sArr[t0 + tid] = m / 127.0f;
        bcInv[tid] = 127.0f / m;
    }
    __syncthreads();

    // quantize + store int8
#pragma unroll
    for (int t = 0; t < 4; t++) {
        float inv = bcInv[t];
        uint4 o;
        o.x = quant4(xv[t][0].x, xv[t][0].y, xv[t][0].z, xv[t][0].w, inv);
        o.y = quant4(xv[t][1].x, xv[t][1].y, xv[t][1].z, xv[t][1].w, inv);
        o.z = quant4(xv[t][2].x, xv[t][2].y, xv[t][2].z, xv[t][2].w, inv);
        o.w = quant4(xv[t][3].x, xv[t][3].y, xv[t][3].z, xv[t][3].w, inv);
        *(uint4*)(Xq + (size_t)(t0 + t) * IN_F + tid * 16) = o;
    }

    // y[t, r] = sum_i x[t,i] * A[r,i]
    float yp[4][RANK] = {};
    const float4* A4 = (const float4*)lA;
#pragma unroll
    for (int r = 0; r < RANK; r++) {
        float4 a0 = A4[(size_t)r * (IN_F / 4) + tid * 4 + 0];
        float4 a1 = A4[(size_t)r * (IN_F / 4) + tid * 4 + 1];
        float4 a2 = A4[(size_t)r * (IN_F / 4) + tid * 4 + 2];
        float4 a3 = A4[(size_t)r * (IN_F / 4) + tid * 4 + 3];
#pragma unroll
        for (int t = 0; t < 4; t++) {
            float acc = 0.f;
            acc += xv[t][0].x * a0.x + xv[t][0].y * a0.y + xv[t][0].z * a0.z + xv[t][0].w * a0.w;
            acc += xv[t][1].x * a1.x + xv[t][1].y * a1.y + xv[t][1].z * a1.z + xv[t][1].w * a1.w;
            acc += xv[t][2].x * a2.x + xv[t][2].y * a2.y + xv[t][2].z * a2.z + xv[t][2].w * a2.w;
            acc += xv[t][3].x * a3.x + xv[t][3].y * a3.y + xv[t][3].z * a3.z + xv[t][3].w * a3.w;
            yp[t][r] += acc;
        }
    }
    __shared__ float yred[4][4][RANK];
#pragma unroll
    for (int t = 0; t < 4; t++)
#pragma unroll
        for (int r = 0; r < RANK; r++) {
            float v = yp[t][r];
#pragma unroll
            for (int off = 32; off > 0; off >>= 1) v += __shfl_down(v, off);
            yp[t][r] = v;
        }
    if (lane == 0)
#pragma unroll
        for (int t = 0; t < 4; t++)
#pragma unroll
            for (int r = 0; r < RANK; r++) yred[wv][t][r] = yp[t][r];
    __syncthreads();
    if (tid < 64) {
        int t = tid >> 4, r = tid & 15;
        float v = yred[0][t][r] + yred[1][t][r] + yred[2][t][r] + yred[3][t][r];
        ypad[(size_t)(t0 + t) * 32 + r] = bf16bits(v);
    } else if (tid < 128) {
        int i = tid - 64;
        int t = i >> 4, r = i & 15;
        ypad[(size_t)(t0 + t) * 32 + 16 + r] = 0;
    }
}

// ---- W ternary -> int8 ----
__global__ __launch_bounds__(256) void k_build_wi8(const int* __restrict__ packed,
                                                   signed char* __restrict__ Wq) {
    int idx = blockIdx.x * 256 + threadIdx.x;  // [0, OUT_F * 256)
    int p = packed[idx];
    uint4 o;
    unsigned int w[4];
#pragma unroll
    for (int g = 0; g < 4; g++) {
        unsigned int word = 0;
#pragma unroll
        for (int j = 0; j < 4; j++) {
            int k = g * 4 + j;
            int b = ((p >> (2 * k)) & 3) - 1;
            word |= (unsigned int)(b & 255) << (8 * j);
        }
        w[g] = word;
    }
    o.x = w[0]; o.y = w[1]; o.z = w[2]; o.w = w[3];
    *(uint4*)(Wq + (size_t)idx * 16) = o;
}

// ---- B lora -> bf16 zero-padded to K=32 ----
__global__ __launch_bounds__(256) void k_bl(const float* __restrict__ lB,
                                            u16* __restrict__ Bl) {
    int o = blockIdx.x * 256 + threadIdx.x;  // [0, OUT_F)
    const float4* B4 = (const float4*)(lB + (size_t)o * RANK);
    float4 b0 = B4[0], b1 = B4[1], b2 = B4[2], b3 = B4[3];
    union { u16 u[32]; uint4 q[4]; } ob;
    ob.u[0] = bf16bits(b0.x); ob.u[1] = bf16bits(b0.y); ob.u[2] = bf16bits(b0.z); ob.u[3] = bf16bits(b0.w);
    ob.u[4] = bf16bits(b1.x); ob.u[5] = bf16bits(b1.y); ob.u[6] = bf16bits(b1.z); ob.u[7] = bf16bits(b1.w);
    ob.u[8] = bf16bits(b2.x); ob.u[9] = bf16bits(b2.y); ob.u[10] = bf16bits(b2.z); ob.u[11] = bf16bits(b2.w);
    ob.u[12] = bf16bits(b3.x); ob.u[13] = bf16bits(b3.y); ob.u[14] = bf16bits(b3.z); ob.u[15] = bf16bits(b3.w);
#pragma unroll
    for (int k = 16; k < 32; k++) ob.u[k] = 0;
    uint4* dst = (uint4*)(Bl + (size_t)o * 32);
    dst[0] = ob.q[0]; dst[1] = ob.q[1]; dst[2] = ob.q[2]; dst[3] = ob.q[3];
}

// ---- main int8 GEMM + fused epilogue (scale, mu, bias, lora MFMA) ----
__global__ __launch_bounds__(256, 2) void k_gemm_i8(const signed char* __restrict__ Xq,
                                                    const signed char* __restrict__ Wq,
                                                    const float* __restrict__ sArr,
                                                    const float* __restrict__ SArr,
                                                    const float* __restrict__ alpha,
                                                    const float* __restrict__ mu,
                                                    const float* __restrict__ bias,
                                                    const u16* __restrict__ ypad,
                                                    const u16* __restrict__ Bl,
                                                    float* __restrict__ out) {
    __shared__ unsigned char smem[16384];
    unsigned char* smA = smem;
    unsigned char* smB = smem + 8192;

    const int tid = threadIdx.x;
    const int lane = tid & 63;
    const int wv = tid >> 6;
    const int wm = (wv >> 1) * 64;
    const int wn = (wv & 1) * 64;
    const int fr = lane & 15;
    const int q16 = (lane >> 4) * 16;     // byte offset into K within a row
    const int wvbase = wv * 1024;

    const int m0 = blockIdx.y * BM;
    const int n0 = blockIdx.x * BN;

    i32x4 acc[4][4] = {};

    for (int k0 = 0; k0 < IN_F; k0 += BKI) {
        __syncthreads();
#pragma unroll
        for (int i = 0; i < 2; i++) {
            int c = i * 256 + tid;
            int row = c >> 2, off = (c & 3) << 4;
            GLDS16(Xq + (size_t)(m0 + row) * IN_F + k0 + off, smA + i * 4096 + wvbase);
        }
#pragma unroll
        for (int i = 0; i < 2; i++) {
            int c = i * 256 + tid;
            int row = c >> 2, off = (c & 3) << 4;
            GLDS16(Wq + (size_t)(n0 + row) * IN_F + k0 + off, smB + i * 4096 + wvbase);
        }
        __syncthreads();

        i32x4 af[4], bf[4];
#pragma unroll
        for (int mt = 0; mt < 4; mt++)
            af[mt] = *(const i32x4*)(smA + (wm + mt * 16 + fr) * BKI + q16);
#pragma unroll
        for (int nt = 0; nt < 4; nt++)
            bf[nt] = *(const i32x4*)(smB + (wn + nt * 16 + fr) * BKI + q16);
#pragma unroll
        for (int mt = 0; mt < 4; mt++)
#pragma unroll
            for (int nt = 0; nt < 4; nt++)
                acc[mt][nt] = __builtin_amdgcn_mfma_i32_16x16x64_i8(af[mt], bf[nt], acc[mt][nt], 0, 0, 0);
    }

    // epilogue: convert int acc -> float with alpha*s, add mu*S + bias
    const int r0 = (lane >> 4) * 4;
    const int c0 = lane & 15;
    f32x4 facc[4][4];
#pragma unroll
    for (int mt = 0; mt < 4; mt++) {
        int rb = m0 + wm + mt * 16 + r0;
        f32x4 sv = *(const f32x4*)(sArr + rb);
        f32x4 Sv = *(const f32x4*)(SArr + rb);
#pragma unroll
        for (int nt = 0; nt < 4; nt++) {
            int col = n0 + wn + nt * 16 + c0;
            float av = alpha[col], mv = mu[col], bv = bias[col];
#pragma unroll
            for (int r = 0; r < 4; r++)
                facc[mt][nt][r] = av * sv[r] * (float)acc[mt][nt][r] + fmaf(mv, Sv[r], bv);
        }
    }

    // lora: one bf16 MFMA pass, C = facc
    __syncthreads();
#pragma unroll
    for (int i = 0; i < 2; i++) {
        int c = i * 256 + tid;
        int row = c >> 2, off = (c & 3) << 4;
        GLDS16((const unsigned char*)ypad + (size_t)(m0 + row) * 64 + off, smA + i * 4096 + wvbase);
        GLDS16((const unsigned char*)Bl + (size_t)(n0 + row) * 64 + off, smB + i * 4096 + wvbase);
    }
    __syncthreads();
    bf16x8 yf[4], blf[4];
#pragma unroll
    for (int mt = 0; mt < 4; mt++)
        yf[mt] = *(const bf16x8*)(smA + (wm + mt * 16 + fr) * 64 + q16);
#pragma unroll
    for (int nt = 0; nt < 4; nt++)
        blf[nt] = *(const bf16x8*)(smB + (wn + nt * 16 + fr) * 64 + q16);
#pragma unroll
    for (int mt = 0; mt < 4; mt++)
#pragma unroll
        for (int nt = 0; nt < 4; nt++)
            facc[mt][nt] = __builtin_amdgcn_mfma_f32_16x16x32_bf16(yf[mt], blf[nt], facc[mt][nt], 0, 0, 0);

    // store
#pragma unroll
    for (int nt = 0; nt < 4; nt++) {
        int col = n0 + wn + nt * 16 + c0;
#pragma unroll
        for (int mt = 0; mt < 4; mt++) {
            int row = m0 + wm + mt * 16 + r0;
            float* op = out + (size_t)row * OUT_F + col;
#pragma unroll
            for (int r = 0; r < 4; r++)
                op[(size_t)r * OUT_F] = facc[mt][nt][r];
        }
    }
}

extern "C" void kernel_launch(void* const* d_in, const int* in_sizes, int n_in,
                              void* d_out, int out_size, void* d_ws, size_t ws_size,
                              hipStream_t stream) {
    const float* x      = (const float*)d_in[0];
    const int*   packed = (const int*)d_in[1];
    const float* alpha  = (const float*)d_in[2];
    const float* mu     = (const float*)d_in[3];
    const float* bias   = (const float*)d_in[4];
    const float* lA     = (const float*)d_in[5];
    const float* lB     = (const float*)d_in[6];
    float* out = (float*)d_out;

    char* p = (char*)d_ws;
    signed char* Wq = (signed char*)p;             p += (size_t)OUT_F * IN_F;        // 16 MiB
    signed char* Xq = (signed char*)p;             p += (size_t)TOKENS * IN_F;       // 32 MiB
    float* sArr = (float*)p;                       p += (size_t)TOKENS * 4;
    float* SArr = (float*)p;                       p += (size_t)TOKENS * 4;
    u16* ypad = (u16*)p;                           p += (size_t)TOKENS * 32 * 2;     // 512 KiB
    u16* Bl = (u16*)p;                             p += (size_t)OUT_F * 32 * 2;      // 256 KiB

    k_rowstat<<<dim3(TOKENS / 4), dim3(256), 0, stream>>>(x, lA, Xq, sArr, SArr, ypad);
    k_build_wi8<<<dim3(OUT_F * 256 / 256), dim3(256), 0, stream>>>(packed, Wq);
    k_bl<<<dim3(OUT_F / 256), dim3(256), 0, stream>>>(lB, Bl);

    dim3 grid(OUT_F / BN, TOKENS / BM);  // (32, 64)
    k_gemm_i8<<<grid, dim3(256), 0, stream>>>(Xq, Wq, sArr, SArr, alpha, mu, bias, ypad, Bl, out);
}

// Round 3
// 403.072 us; speedup vs baseline: 1.5883x; 1.2337x over previous
//
#include <hip/hip_runtime.h>
#include <stdint.h>

#define IN_F   4096
#define OUT_F  4096
#define TOKENS 8192
#define RANK   16

#define BM 128
#define BN 128
#define BKI 64   // i8 K-tile (16x16x64 MFMA)

typedef unsigned short u16;
typedef __attribute__((ext_vector_type(8))) short bf16x8;
typedef __attribute__((ext_vector_type(4))) float f32x4;
typedef __attribute__((ext_vector_type(4))) int i32x4;

// async global->LDS, 16B/lane; LDS dest = wave-uniform base, HW adds lane*16
#define GLDS16(g, l) __builtin_amdgcn_global_load_lds( \
    (__attribute__((address_space(1))) void*)(g),      \
    (__attribute__((address_space(3))) void*)(l), 16, 0, 0)

__device__ __forceinline__ u16 bf16bits(float f) {
    unsigned int u = __builtin_bit_cast(unsigned int, f);
    unsigned int lsb = (u >> 16) & 1u;
    u += 0x7fffu + lsb;
    return (u16)(u >> 16);
}

__device__ __forceinline__ unsigned int quant4(float a, float b, float c, float d, float inv) {
    int qa = __float2int_rn(a * inv); qa = max(-127, min(127, qa));
    int qb = __float2int_rn(b * inv); qb = max(-127, min(127, qb));
    int qc = __float2int_rn(c * inv); qc = max(-127, min(127, qc));
    int qd = __float2int_rn(d * inv); qd = max(-127, min(127, qd));
    return (qa & 255) | ((qb & 255) << 8) | ((qc & 255) << 16) | ((qd & 255) << 24);
}

// ---- per-token absmax/sum + int8 quantize. One block per token. ----
__global__ __launch_bounds__(256) void k_quant(const float* __restrict__ X,
                                               signed char* __restrict__ Xq,
                                               float* __restrict__ sArr,
                                               float* __restrict__ SArr) {
    const int t = blockIdx.x;
    const int tid = threadIdx.x;
    const int lane = tid & 63;
    const int wv = tid >> 6;

    const float4* X4 = (const float4*)(X + (size_t)t * IN_F);
    float4 v[4];
#pragma unroll
    for (int j = 0; j < 4; j++) v[j] = X4[tid * 4 + j];

    float s = 0.f, m = 0.f;
#pragma unroll
    for (int j = 0; j < 4; j++) {
        s += v[j].x + v[j].y + v[j].z + v[j].w;
        m = fmaxf(m, fmaxf(fmaxf(fabsf(v[j].x), fabsf(v[j].y)),
                           fmaxf(fabsf(v[j].z), fabsf(v[j].w))));
    }
#pragma unroll
    for (int off = 32; off > 0; off >>= 1) {
        s += __shfl_down(s, off);
        m = fmaxf(m, __shfl_down(m, off));
    }
    __shared__ float rs[4], rm[4];
    if (lane == 0) { rs[wv] = s; rm[wv] = m; }
    __syncthreads();
    float S = rs[0] + rs[1] + rs[2] + rs[3];
    float M = fmaxf(fmaxf(rm[0], rm[1]), fmaxf(rm[2], rm[3]));
    M = fmaxf(M, 1e-20f);
    if (tid == 0) { SArr[t] = S; sArr[t] = M / 127.0f; }

    float inv = 127.0f / M;
    uint4 o;
    o.x = quant4(v[0].x, v[0].y, v[0].z, v[0].w, inv);
    o.y = quant4(v[1].x, v[1].y, v[1].z, v[1].w, inv);
    o.z = quant4(v[2].x, v[2].y, v[2].z, v[2].w, inv);
    o.w = quant4(v[3].x, v[3].y, v[3].z, v[3].w, inv);
    *(uint4*)(Xq + (size_t)t * IN_F + tid * 16) = o;
}

// ---- quantize lora_A rows to int8 (per-row scale). One block per rank row. ----
__global__ __launch_bounds__(256) void k_aq(const float* __restrict__ lA,
                                            signed char* __restrict__ Aq,
                                            float* __restrict__ aScale) {
    const int r = blockIdx.x;
    const int tid = threadIdx.x;
    const int lane = tid & 63;
    const int wv = tid >> 6;

    const float4* A4 = (const float4*)(lA + (size_t)r * IN_F);
    float4 v[4];
#pragma unroll
    for (int j = 0; j < 4; j++) v[j] = A4[tid * 4 + j];

    float m = 0.f;
#pragma unroll
    for (int j = 0; j < 4; j++)
        m = fmaxf(m, fmaxf(fmaxf(fabsf(v[j].x), fabsf(v[j].y)),
                           fmaxf(fabsf(v[j].z), fabsf(v[j].w))));
#pragma unroll
    for (int off = 32; off > 0; off >>= 1) m = fmaxf(m, __shfl_down(m, off));
    __shared__ float rm[4];
    if (lane == 0) rm[wv] = m;
    __syncthreads();
    float M = fmaxf(fmaxf(rm[0], rm[1]), fmaxf(rm[2], rm[3]));
    M = fmaxf(M, 1e-20f);
    if (tid == 0) aScale[r] = M / 127.0f;

    float inv = 127.0f / M;
    uint4 o;
    o.x = quant4(v[0].x, v[0].y, v[0].z, v[0].w, inv);
    o.y = quant4(v[1].x, v[1].y, v[1].z, v[1].w, inv);
    o.z = quant4(v[2].x, v[2].y, v[2].z, v[2].w, inv);
    o.w = quant4(v[3].x, v[3].y, v[3].z, v[3].w, inv);
    *(uint4*)(Aq + (size_t)r * IN_F + tid * 16) = o;
}

// ---- y = x * A^T via i8 MFMA: one wave per 16 tokens, N=16 ranks. ----
__global__ __launch_bounds__(64) void k_lora_y(const signed char* __restrict__ Xq,
                                               const signed char* __restrict__ Aq,
                                               const float* __restrict__ sArr,
                                               const float* __restrict__ aScale,
                                               u16* __restrict__ ypad) {
    const int lane = threadIdx.x;
    const int t0 = blockIdx.x * 16;
    const int fr = lane & 15;
    const int q16 = (lane >> 4) * 16;

    i32x4 acc = {};
    const signed char* xrow = Xq + (size_t)(t0 + fr) * IN_F + q16;
    const signed char* arow = Aq + (size_t)fr * IN_F + q16;
#pragma unroll 8
    for (int k0 = 0; k0 < IN_F; k0 += BKI) {
        i32x4 af = *(const i32x4*)(xrow + k0);
        i32x4 bf = *(const i32x4*)(arow + k0);
        acc = __builtin_amdgcn_mfma_i32_16x16x64_i8(af, bf, acc, 0, 0, 0);
    }

    const int c0 = lane & 15;          // rank
    const int r0 = (lane >> 4) * 4;    // token within group
    float asc = aScale[c0];
#pragma unroll
    for (int r = 0; r < 4; r++) {
        int t = t0 + r0 + r;
        float y = sArr[t] * asc * (float)acc[r];
        ypad[(size_t)t * 32 + c0] = bf16bits(y);
        ypad[(size_t)t * 32 + 16 + c0] = 0;
    }
}

// ---- W ternary -> int8 ----
__global__ __launch_bounds__(256) void k_build_wi8(const int* __restrict__ packed,
                                                   signed char* __restrict__ Wq) {
    int idx = blockIdx.x * 256 + threadIdx.x;  // [0, OUT_F * 256)
    int p = packed[idx];
    uint4 o;
    unsigned int w[4];
#pragma unroll
    for (int g = 0; g < 4; g++) {
        unsigned int word = 0;
#pragma unroll
        for (int j = 0; j < 4; j++) {
            int k = g * 4 + j;
            int b = ((p >> (2 * k)) & 3) - 1;
            word |= (unsigned int)(b & 255) << (8 * j);
        }
        w[g] = word;
    }
    o.x = w[0]; o.y = w[1]; o.z = w[2]; o.w = w[3];
    *(uint4*)(Wq + (size_t)idx * 16) = o;
}

// ---- B lora -> bf16 zero-padded to K=32 ----
__global__ __launch_bounds__(256) void k_bl(const float* __restrict__ lB,
                                            u16* __restrict__ Bl) {
    int o = blockIdx.x * 256 + threadIdx.x;  // [0, OUT_F)
    const float4* B4 = (const float4*)(lB + (size_t)o * RANK);
    float4 b0 = B4[0], b1 = B4[1], b2 = B4[2], b3 = B4[3];
    union { u16 u[32]; uint4 q[4]; } ob;
    ob.u[0] = bf16bits(b0.x); ob.u[1] = bf16bits(b0.y); ob.u[2] = bf16bits(b0.z); ob.u[3] = bf16bits(b0.w);
    ob.u[4] = bf16bits(b1.x); ob.u[5] = bf16bits(b1.y); ob.u[6] = bf16bits(b1.z); ob.u[7] = bf16bits(b1.w);
    ob.u[8] = bf16bits(b2.x); ob.u[9] = bf16bits(b2.y); ob.u[10] = bf16bits(b2.z); ob.u[11] = bf16bits(b2.w);
    ob.u[12] = bf16bits(b3.x); ob.u[13] = bf16bits(b3.y); ob.u[14] = bf16bits(b3.z); ob.u[15] = bf16bits(b3.w);
#pragma unroll
    for (int k = 16; k < 32; k++) ob.u[k] = 0;
    uint4* dst = (uint4*)(Bl + (size_t)o * 32);
    dst[0] = ob.q[0]; dst[1] = ob.q[1]; dst[2] = ob.q[2]; dst[3] = ob.q[3];
}

// ---- main int8 GEMM + fused epilogue (scale, mu, bias, lora MFMA) ----
__global__ __launch_bounds__(256, 2) void k_gemm_i8(const signed char* __restrict__ Xq,
                                                    const signed char* __restrict__ Wq,
                                                    const float* __restrict__ sArr,
                                                    const float* __restrict__ SArr,
                                                    const float* __restrict__ alpha,
                                                    const float* __restrict__ mu,
                                                    const float* __restrict__ bias,
                                                    const u16* __restrict__ ypad,
                                                    const u16* __restrict__ Bl,
                                                    float* __restrict__ out) {
    __shared__ unsigned char smem[16384];
    unsigned char* smA = smem;
    unsigned char* smB = smem + 8192;

    const int tid = threadIdx.x;
    const int lane = tid & 63;
    const int wv = tid >> 6;
    const int wm = (wv >> 1) * 64;
    const int wn = (wv & 1) * 64;
    const int fr = lane & 15;
    const int q16 = (lane >> 4) * 16;     // byte offset into K within a row
    const int wvbase = wv * 1024;

    const int m0 = blockIdx.y * BM;
    const int n0 = blockIdx.x * BN;

    i32x4 acc[4][4] = {};

    for (int k0 = 0; k0 < IN_F; k0 += BKI) {
        __syncthreads();
#pragma unroll
        for (int i = 0; i < 2; i++) {
            int c = i * 256 + tid;
            int row = c >> 2, off = (c & 3) << 4;
            GLDS16(Xq + (size_t)(m0 + row) * IN_F + k0 + off, smA + i * 4096 + wvbase);
        }
#pragma unroll
        for (int i = 0; i < 2; i++) {
            int c = i * 256 + tid;
            int row = c >> 2, off = (c & 3) << 4;
            GLDS16(Wq + (size_t)(n0 + row) * IN_F + k0 + off, smB + i * 4096 + wvbase);
        }
        __syncthreads();

        i32x4 af[4], bf[4];
#pragma unroll
        for (int mt = 0; mt < 4; mt++)
            af[mt] = *(const i32x4*)(smA + (wm + mt * 16 + fr) * BKI + q16);
#pragma unroll
        for (int nt = 0; nt < 4; nt++)
            bf[nt] = *(const i32x4*)(smB + (wn + nt * 16 + fr) * BKI + q16);
#pragma unroll
        for (int mt = 0; mt < 4; mt++)
#pragma unroll
            for (int nt = 0; nt < 4; nt++)
                acc[mt][nt] = __builtin_amdgcn_mfma_i32_16x16x64_i8(af[mt], bf[nt], acc[mt][nt], 0, 0, 0);
    }

    // epilogue: convert int acc -> float with alpha*s, add mu*S + bias
    const int r0 = (lane >> 4) * 4;
    const int c0 = lane & 15;
    f32x4 facc[4][4];
#pragma unroll
    for (int mt = 0; mt < 4; mt++) {
        int rb = m0 + wm + mt * 16 + r0;
        f32x4 sv = *(const f32x4*)(sArr + rb);
        f32x4 Sv = *(const f32x4*)(SArr + rb);
#pragma unroll
        for (int nt = 0; nt < 4; nt++) {
            int col = n0 + wn + nt * 16 + c0;
            float av = alpha[col], mv = mu[col], bv = bias[col];
#pragma unroll
            for (int r = 0; r < 4; r++)
                facc[mt][nt][r] = av * sv[r] * (float)acc[mt][nt][r] + fmaf(mv, Sv[r], bv);
        }
    }

    // lora: one bf16 MFMA pass, C = facc
    __syncthreads();
#pragma unroll
    for (int i = 0; i < 2; i++) {
        int c = i * 256 + tid;
        int row = c >> 2, off = (c & 3) << 4;
        GLDS16((const unsigned char*)ypad + (size_t)(m0 + row) * 64 + off, smA + i * 4096 + wvbase);
        GLDS16((const unsigned char*)Bl + (size_t)(n0 + row) * 64 + off, smB + i * 4096 + wvbase);
    }
    __syncthreads();
    bf16x8 yf[4], blf[4];
#pragma unroll
    for (int mt = 0; mt < 4; mt++)
        yf[mt] = *(const bf16x8*)(smA + (wm + mt * 16 + fr) * 64 + q16);
#pragma unroll
    for (int nt = 0; nt < 4; nt++)
        blf[nt] = *(const bf16x8*)(smB + (wn + nt * 16 + fr) * 64 + q16);
#pragma unroll
    for (int mt = 0; mt < 4; mt++)
#pragma unroll
        for (int nt = 0; nt < 4; nt++)
            facc[mt][nt] = __builtin_amdgcn_mfma_f32_16x16x32_bf16(yf[mt], blf[nt], facc[mt][nt], 0, 0, 0);

    // store
#pragma unroll
    for (int nt = 0; nt < 4; nt++) {
        int col = n0 + wn + nt * 16 + c0;
#pragma unroll
        for (int mt = 0; mt < 4; mt++) {
            int row = m0 + wm + mt * 16 + r0;
            float* op = out + (size_t)row * OUT_F + col;
#pragma unroll
            for (int r = 0; r < 4; r++)
                op[(size_t)r * OUT_F] = facc[mt][nt][r];
        }
    }
}

extern "C" void kernel_launch(void* const* d_in, const int* in_sizes, int n_in,
                              void* d_out, int out_size, void* d_ws, size_t ws_size,
                              hipStream_t stream) {
    const float* x      = (const float*)d_in[0];
    const int*   packed = (const int*)d_in[1];
    const float* alpha  = (const float*)d_in[2];
    const float* mu     = (const float*)d_in[3];
    const float* bias   = (const float*)d_in[4];
    const float* lA     = (const float*)d_in[5];
    const float* lB     = (const float*)d_in[6];
    float* out = (float*)d_out;

    char* p = (char*)d_ws;
    signed char* Wq = (signed char*)p;             p += (size_t)OUT_F * IN_F;        // 16 MiB
    signed char* Xq = (signed char*)p;             p += (size_t)TOKENS * IN_F;       // 32 MiB
    float* sArr = (float*)p;                       p += (size_t)TOKENS * 4;
    float* SArr = (float*)p;                       p += (size_t)TOKENS * 4;
    u16* ypad = (u16*)p;                           p += (size_t)TOKENS * 32 * 2;     // 512 KiB
    u16* Bl = (u16*)p;                             p += (size_t)OUT_F * 32 * 2;      // 256 KiB
    signed char* Aq = (signed char*)p;             p += (size_t)RANK * IN_F;         // 64 KiB
    float* aScale = (float*)p;                     p += RANK * 4;

    k_quant<<<dim3(TOKENS), dim3(256), 0, stream>>>(x, Xq, sArr, SArr);
    k_aq<<<dim3(RANK), dim3(256), 0, stream>>>(lA, Aq, aScale);
    k_lora_y<<<dim3(TOKENS / 16), dim3(64), 0, stream>>>(Xq, Aq, sArr, aScale, ypad);
    k_build_wi8<<<dim3(OUT_F * 256 / 256), dim3(256), 0, stream>>>(packed, Wq);
    k_bl<<<dim3(OUT_F / 256), dim3(256), 0, stream>>>(lB, Bl);

    dim3 grid(OUT_F / BN, TOKENS / BM);  // (32, 64)
    k_gemm_i8<<<grid, dim3(256), 0, stream>>>(Xq, Wq, sArr, SArr, alpha, mu, bias, ypad, Bl, out);
}